// Round 20
// baseline (91.637 us; speedup 1.0000x reference)
//
#include <hip/hip_runtime.h>
#include <math.h>

namespace {

constexpr int Bn = 4, Cn = 96, Hn = 64, Wn = 64, Ln = 4096, Din = 192;
constexpr int Kn = 4, Rn = 6, Dmlp = 384;
constexpr int NCH = 128, CLEN = 32;   // 128 chunks * 32 = L

typedef short short8 __attribute__((ext_vector_type(8)));
typedef float f32x4 __attribute__((ext_vector_type(4)));

__device__ __forceinline__ float siluf_(float x) {
  return x / (1.f + __expf(-x));
}
__device__ __forceinline__ float geluf_(float x) {
  return 0.5f * x * (1.f + erff(x * 0.7071067811865476f));
}
__device__ __forceinline__ unsigned short f2bf(float f) {
  unsigned u = __float_as_uint(f);
  unsigned r = 0x7fffu + ((u >> 16) & 1u);
  return (unsigned short)((u + r) >> 16);
}
__device__ __forceinline__ float bf2f(unsigned short v) {
  return __uint_as_float(((unsigned)v) << 16);
}

// ---------------------------------------------------------------------------
// K1: blocks 0..511: LayerNorm(96) + in_proj MFMA; outputs staged in LDS and
// written with coalesced short8 stores. Blocks 512..535: convert x_proj.
// LDS union: sx f32[32*97] (12416B) -> sout bf16[192][40] (15360B).
// ---------------------------------------------------------------------------
__global__ __launch_bounds__(256) void k1_ln_inproj(
    const float* __restrict__ x, const float* __restrict__ gam,
    const float* __restrict__ bet, const float* __restrict__ win,
    const float* __restrict__ wxp, unsigned short* __restrict__ ucpb,
    unsigned short* __restrict__ wxpb) {
  const int tid = threadIdx.x;
  if (blockIdx.x >= 512) {
    int t = (blockIdx.x - 512) * 256 + tid;   // [0, 6144)
    wxpb[t] = f2bf(wxp[t]);
    return;
  }

  __shared__ __align__(16) char su_mem[15360];
  float* sx = (float*)su_mem;                      // [32][97]
  unsigned short* sout = (unsigned short*)su_mem;  // [192][40]
  __shared__ __align__(16) unsigned short smb[32 * 104];
  __shared__ __align__(16) unsigned short swin[192 * 96];
  const int p0 = blockIdx.x * 32;
  const int b = p0 >> 12, pl0 = p0 & (Ln - 1);

  for (int e = tid; e < 4608; e += 256) {
    float4 w4 = reinterpret_cast<const float4*>(win)[e];
    uint2 pk;
    pk.x = (unsigned)f2bf(w4.x) | ((unsigned)f2bf(w4.y) << 16);
    pk.y = (unsigned)f2bf(w4.z) | ((unsigned)f2bf(w4.w) << 16);
    *reinterpret_cast<uint2*>(&swin[e * 4]) = pk;
  }

  for (int f = tid; f < 32 * 96; f += 256) {
    int c = f >> 5, pp = f & 31;
    sx[pp * 97 + c] = x[((size_t)b * Cn + c) * Ln + pl0 + pp];
  }
  __syncthreads();
  {
    const int pp = tid >> 3, t8 = tid & 7;
    float s = 0.f;
    for (int c = t8 * 12; c < t8 * 12 + 12; ++c) s += sx[pp * 97 + c];
    s += __shfl_xor(s, 1, 8); s += __shfl_xor(s, 2, 8); s += __shfl_xor(s, 4, 8);
    float m = s * (1.f / 96.f);
    float v = 0.f;
    for (int c = t8 * 12; c < t8 * 12 + 12; ++c) {
      float t = sx[pp * 97 + c] - m; v += t * t;
    }
    v += __shfl_xor(v, 1, 8); v += __shfl_xor(v, 2, 8); v += __shfl_xor(v, 4, 8);
    float rs = rsqrtf(v * (1.f / 96.f) + 1e-5f);
    for (int c = t8 * 12; c < t8 * 12 + 12; ++c)
      sx[pp * 97 + c] = (sx[pp * 97 + c] - m) * rs * gam[c] + bet[c];
  }
  __syncthreads();
  for (int f = tid; f < 32 * 96; f += 256) {
    int pp = f / 96, c = f % 96;
    smb[pp * 104 + c] = f2bf(sx[pp * 97 + c]);
  }
  __syncthreads();   // sx dead from here; sout may overwrite its region

  const int wv = tid >> 6, lane = tid & 63;
  const int l15 = lane & 15, lhi = lane >> 4;
  const int mt = wv & 1, nbase = (wv >> 1) * 6;
  for (int t = 0; t < 6; ++t) {
    const int n0 = (nbase + t) * 16;
    f32x4 acc = {0.f, 0.f, 0.f, 0.f};
#pragma unroll
    for (int kk = 0; kk < 3; ++kk) {
      short8 av = *reinterpret_cast<const short8*>(
          &smb[(16 * mt + l15) * 104 + kk * 32 + lhi * 8]);
      short8 bv = *reinterpret_cast<const short8*>(
          &swin[(n0 + l15) * 96 + kk * 32 + lhi * 8]);
      acc = __builtin_amdgcn_mfma_f32_16x16x32_bf16(av, bv, acc, 0, 0, 0);
    }
    const int j = n0 + l15;
#pragma unroll
    for (int r = 0; r < 4; ++r)
      sout[j * 40 + 16 * mt + lhi * 4 + r] = f2bf(acc[r]);
  }
  __syncthreads();

  for (int f = tid; f < 768; f += 256) {
    int c = f >> 2, seg = (f & 3) * 8;
    short8 v = *reinterpret_cast<const short8*>(&sout[c * 40 + seg]);
    *reinterpret_cast<short8*>(
        &ucpb[((size_t)b * Din + c) * Ln + pl0 + seg]) = v;
  }
}

// ---------------------------------------------------------------------------
// K2a: depthwise 3x3 conv + SiLU -> utb (pixel-major bf16). Channel-split.
// ---------------------------------------------------------------------------
__global__ __launch_bounds__(512) void k2a_conv(
    const unsigned short* __restrict__ ucpb, const float* __restrict__ cw,
    unsigned short* __restrict__ utb) {
  __shared__ float su[64 * 97];
  const int tid = threadIdx.x;
  const int bid = blockIdx.x;
  const int half = bid & 1, bh = bid >> 1;
  const int b = bh >> 6, h = bh & 63;
  const int w = tid & 63, wg = tid >> 6;
  const int d0 = half * 96;

  for (int dd = 0; dd < 12; ++dd) {
    int dl = wg * 12 + dd;
    int d = d0 + dl;
    const unsigned short* base = &ucpb[((size_t)b * Din + d) * Ln];
    float r0 = (h > 0) ? bf2f(base[(h - 1) * 64 + w]) : 0.f;
    float r1 = bf2f(base[h * 64 + w]);
    float r2 = (h < 63) ? bf2f(base[(h + 1) * 64 + w]) : 0.f;
    const float* wt = &cw[d * 9];
    float rl, rr, acc;
    rl = __shfl(r0, (w + 63) & 63); if (w == 0) rl = 0.f;
    rr = __shfl(r0, (w + 1) & 63);  if (w == 63) rr = 0.f;
    acc = rl * wt[0] + r0 * wt[1] + rr * wt[2];
    rl = __shfl(r1, (w + 63) & 63); if (w == 0) rl = 0.f;
    rr = __shfl(r1, (w + 1) & 63);  if (w == 63) rr = 0.f;
    acc += rl * wt[3] + r1 * wt[4] + rr * wt[5];
    rl = __shfl(r2, (w + 63) & 63); if (w == 0) rl = 0.f;
    rr = __shfl(r2, (w + 1) & 63);  if (w == 63) rr = 0.f;
    acc += rl * wt[6] + r2 * wt[7] + rr * wt[8];
    su[w * 97 + dl] = siluf_(acc);
  }
  __syncthreads();

  for (int f = tid; f < 768; f += 512) {
    int pp = f / 12, c8 = (f % 12) * 8;
    short8 v;
#pragma unroll
    for (int j = 0; j < 8; ++j) v[j] = (short)f2bf(su[pp * 97 + c8 + j]);
    *reinterpret_cast<short8*>(
        &utb[((size_t)b * Ln + h * 64 + pp) * Din + d0 + c8]) = v;
  }
}

__device__ __forceinline__ int scan_pixel(int k, int l) {
  if (k == 0) return l;
  if (k == 1) return ((l & 63) << 6) | (l >> 6);
  if (k == 2) return Ln - 1 - l;
  int m2 = Ln - 1 - l;
  return ((m2 & 63) << 6) | (m2 >> 6);
}

// ---------------------------------------------------------------------------
// Shared scan-block prologue: stage chunk's u rows (scan order) into LDS,
// compute own-direction x_proj via MFMA into sdb[32][8].
// ---------------------------------------------------------------------------
__device__ __forceinline__ void scan_stage(
    const unsigned short* __restrict__ ub,
    const unsigned short* __restrict__ wxpb, int k, int l0, int d,
    unsigned short* su, float* sdb) {
  for (int e = d; e < 768; e += 192) {
    int i = e / 24, c8 = (e % 24) * 8;
    int p = scan_pixel(k, l0 + i);
    *reinterpret_cast<short8*>(&su[i * 200 + c8]) =
        *reinterpret_cast<const short8*>(&ub[(size_t)p * 192 + c8]);
  }
  __syncthreads();
  const int wv3 = d >> 6, lane = d & 63;
  const int l15 = lane & 15, lhi = lane >> 4;
  if (wv3 < 2) {
    const int mt = wv3;
    const int n0 = (k >> 1) * 16;
    f32x4 acc = {0.f, 0.f, 0.f, 0.f};
#pragma unroll
    for (int kk = 0; kk < 6; ++kk) {
      short8 av = *reinterpret_cast<const short8*>(
          &su[(16 * mt + l15) * 200 + kk * 32 + lhi * 8]);
      short8 bv = *reinterpret_cast<const short8*>(
          &wxpb[(size_t)(n0 + l15) * 192 + kk * 32 + lhi * 8]);
      acc = __builtin_amdgcn_mfma_f32_16x16x32_bf16(av, bv, acc, 0, 0, 0);
    }
    if ((l15 >> 3) == (k & 1)) {
      const int c8 = l15 & 7;
#pragma unroll
      for (int r = 0; r < 4; ++r)
        sdb[(16 * mt + lhi * 4 + r) * 8 + c8] = acc[r];
    }
  }
  __syncthreads();
}

// ---------------------------------------------------------------------------
// K4: single heavy scan pass — fused x_proj + local carry-free scan.
// Direct coalesced per-element stores for yd AND pcg (no LDS staging):
// LDS = 13.8KB -> 8 blocks/CU (was 6).
// ---------------------------------------------------------------------------
__global__ __launch_bounds__(192) void k4_scanY(
    const unsigned short* __restrict__ utb,
    const unsigned short* __restrict__ wxpb, const float* __restrict__ wdtg,
    const float* __restrict__ bdtg, const float* __restrict__ alog,
    const float* __restrict__ dsg, float* __restrict__ apb,
    float* __restrict__ heb, unsigned short* __restrict__ yd,
    unsigned short* __restrict__ pcg) {
  __shared__ __align__(16) unsigned short su[32 * 200];
  __shared__ __align__(16) float sdb[CLEN * 8];
  const int bid = blockIdx.x;
  const int ch = bid & (NCH - 1);
  const int bk = bid / NCH;
  const int b = bk >> 2, k = bk & 3;
  const int d = threadIdx.x;
  const int l0 = ch * CLEN;

  float wdt[6];
#pragma unroll
  for (int r = 0; r < 6; ++r) wdt[r] = wdtg[(k * Din + d) * 6 + r];
  const float bdt = bdtg[k * Din + d];
  const float Av = -__expf(alog[k * Din + d]);
  const bool fast = (Av == -1.0f);
  const float Dv = dsg[k * Din + d];
  unsigned short* yk = &yd[((size_t)bk * Ln + l0) * Din + d];
  unsigned short* pk = &pcg[((size_t)bk * Ln + l0) * Din + d];

  scan_stage(&utb[(size_t)b * Ln * Din], wxpb, k, l0, d, su, sdb);

  float h = 0.f, P = 1.f;
  for (int i0 = 0; i0 < CLEN; i0 += 8) {
    float U[8];
#pragma unroll
    for (int j = 0; j < 8; ++j) U[j] = bf2f(su[(i0 + j) * 200 + d]);
#pragma unroll
    for (int j = 0; j < 8; ++j) {
      float4 qa = *reinterpret_cast<const float4*>(&sdb[(i0 + j) * 8]);
      float4 qb = *reinterpret_cast<const float4*>(&sdb[(i0 + j) * 8 + 4]);
      float xdt = bdt;
      xdt = fmaf(qa.x, wdt[0], xdt); xdt = fmaf(qa.y, wdt[1], xdt);
      xdt = fmaf(qa.z, wdt[2], xdt); xdt = fmaf(qa.w, wdt[3], xdt);
      xdt = fmaf(qb.x, wdt[4], xdt); xdt = fmaf(qb.y, wdt[5], xdt);
      float ex = __expf(-fabsf(xdt));
      float dt = fmaxf(xdt, 0.f) + __logf(1.f + ex);
      float a;
      if (fast) {
        float num = (xdt > 0.f) ? ex : 1.f;
        a = num * __builtin_amdgcn_rcpf(1.f + ex);
      } else {
        a = __expf(dt * Av);
      }
      float bbv = dt * qb.z * U[j];
      h = fmaf(a, h, bbv);
      P *= a;
      yk[(size_t)(i0 + j) * Din] = f2bf(h * qb.w + Dv * U[j]);
      pk[(size_t)(i0 + j) * Din] = f2bf(P * qb.w);
    }
  }
  size_t o = ((size_t)bk * NCH + ch) * Din + d;
  apb[o] = P;
  heb[o] = h;
}

// ---------------------------------------------------------------------------
// K5: blocks 0..11: chunk carries with batch-8 prefetch. Blocks 12..371:
// convert w1/w2/wout to bf16.
// ---------------------------------------------------------------------------
__global__ __launch_bounds__(256) void k5_carry(
    const float* __restrict__ apb, const float* __restrict__ heb,
    float* __restrict__ cin, const float* __restrict__ w1,
    const float* __restrict__ w2, const float* __restrict__ wout,
    unsigned short* __restrict__ w1b, unsigned short* __restrict__ w2b,
    unsigned short* __restrict__ woutb) {
  if (blockIdx.x >= 12) {
    int t = (blockIdx.x - 12) * 256 + threadIdx.x;   // [0, 92160)
    if (t < 36864) w1b[t] = f2bf(w1[t]);
    else if (t < 73728) w2b[t - 36864] = f2bf(w2[t - 36864]);
    else woutb[t - 73728] = f2bf(wout[t - 73728]);
    return;
  }
  int t = blockIdx.x * 256 + threadIdx.x;
  if (t >= Bn * Kn * Din) return;
  int bk = t / Din, d = t % Din;
  const float* ap_ = &apb[(size_t)bk * NCH * Din + d];
  const float* hp_ = &heb[(size_t)bk * NCH * Din + d];
  float* cp_ = &cin[(size_t)bk * NCH * Din + d];
  float c = 0.f;
  for (int ch = 0; ch < NCH; ch += 8) {
    float A[8], H[8];
#pragma unroll
    for (int j = 0; j < 8; ++j) {
      A[j] = ap_[(size_t)(ch + j) * Din];
      H[j] = hp_[(size_t)(ch + j) * Din];
    }
#pragma unroll
    for (int j = 0; j < 8; ++j) {
      cp_[(size_t)(ch + j) * Din] = c;
      c = fmaf(A[j], c, H[j]);
    }
  }
}

// ---------------------------------------------------------------------------
// K78: fused tail. x residual loads hoisted to kernel start (latency hidden
// under merge + LN phases).
// ---------------------------------------------------------------------------
__global__ __launch_bounds__(256) void k78_tail(
    const unsigned short* __restrict__ yd,
    const unsigned short* __restrict__ pcg, const float* __restrict__ cin,
    const float* __restrict__ gam, const float* __restrict__ bet,
    const unsigned short* __restrict__ woutb, const float* __restrict__ g2,
    const float* __restrict__ b2, const unsigned short* __restrict__ w1b,
    const float* __restrict__ b1f, const unsigned short* __restrict__ w2b,
    const float* __restrict__ b2f, const float* __restrict__ x,
    float* __restrict__ out) {
  __shared__ __align__(16) char smem[50304];
  float* SY = (float*)smem;
  unsigned short* SB7 = (unsigned short*)(smem + 24704);
  unsigned short* SH = (unsigned short*)(smem + 37504);
  float* SZ = (float*)smem;
  unsigned short* SM = (unsigned short*)(smem + 12416);
  float* SMLP = (float*)(smem + 24704);

  const int tid = threadIdx.x;
  const int p0 = blockIdx.x * 32;
  const int b = p0 >> 12, pl0 = p0 & (Ln - 1);
  const int wv = tid >> 6, lane = tid & 63;
  const int l15 = lane & 15, lhi = lane >> 4;

  // --- 0. issue x residual loads early (hidden under phases 1-3) ---
  float xr[12];
#pragma unroll
  for (int it = 0; it < 12; ++it) {
    int f = tid + it * 256;
    int c = f >> 5, pp = f & 31;
    xr[it] = x[((size_t)b * Cn + c) * Ln + pl0 + pp];
  }

  // --- 1. merge 4 directions with carry correction -> SY ---
  for (int f = tid; f < 32 * 24; f += 256) {
    int pp = f / 24, c8 = (f % 24) * 8;
    int p = pl0 + pp;
    int l1 = ((p & 63) << 6) | (p >> 6);
    float s[8];
#pragma unroll
    for (int j = 0; j < 8; ++j) s[j] = 0.f;
#pragma unroll
    for (int k = 0; k < 4; ++k) {
      int l = (k == 0) ? p : (k == 1) ? l1 : (k == 2) ? (Ln - 1 - p)
                                                      : (Ln - 1 - l1);
      size_t base = ((size_t)(b * 4 + k) * Ln + l) * 192 + c8;
      short8 py = *reinterpret_cast<const short8*>(&yd[base]);
      short8 pc = *reinterpret_cast<const short8*>(&pcg[base]);
      const float* cp =
          &cin[((size_t)(b * 4 + k) * NCH + (l >> 5)) * 192 + c8];
      float4 ca = *reinterpret_cast<const float4*>(cp);
      float4 cb = *reinterpret_cast<const float4*>(cp + 4);
      float cv[8] = {ca.x, ca.y, ca.z, ca.w, cb.x, cb.y, cb.z, cb.w};
#pragma unroll
      for (int j = 0; j < 8; ++j)
        s[j] += bf2f((unsigned short)py[j]) +
                bf2f((unsigned short)pc[j]) * cv[j];
    }
#pragma unroll
    for (int j = 0; j < 8; ++j) SY[pp * 193 + c8 + j] = s[j];
  }
  __syncthreads();

  // --- 2. LN(192) -> SB7 (bf16) ---
  {
    const int pp = tid >> 3, t8 = tid & 7;
    float s = 0.f;
    for (int d2 = t8 * 24; d2 < t8 * 24 + 24; ++d2) s += SY[pp * 193 + d2];
    s += __shfl_xor(s, 1, 8); s += __shfl_xor(s, 2, 8); s += __shfl_xor(s, 4, 8);
    float m = s * (1.f / 192.f);
    float v = 0.f;
    for (int d2 = t8 * 24; d2 < t8 * 24 + 24; ++d2) {
      float t = SY[pp * 193 + d2] - m; v += t * t;
    }
    v += __shfl_xor(v, 1, 8); v += __shfl_xor(v, 2, 8); v += __shfl_xor(v, 4, 8);
    float rs = rsqrtf(v * (1.f / 192.f) + 1e-5f);
    for (int d2 = t8 * 24; d2 < t8 * 24 + 24; ++d2)
      SB7[pp * 200 + d2] = f2bf((SY[pp * 193 + d2] - m) * rs * gam[d2] + bet[d2]);
  }
  __syncthreads();

  // --- 3. out_proj MFMA (K=192) -> SZ ---
  for (int q = 0; q < 3; ++q) {
    const int tt = wv + q * 4;
    const int mt = tt & 1, c0 = (tt >> 1) * 16;
    f32x4 acc = {0.f, 0.f, 0.f, 0.f};
#pragma unroll
    for (int kk = 0; kk < 6; ++kk) {
      short8 av = *reinterpret_cast<const short8*>(
          &SB7[(16 * mt + l15) * 200 + kk * 32 + lhi * 8]);
      short8 bv = *reinterpret_cast<const short8*>(
          &woutb[(size_t)(c0 + l15) * 192 + kk * 32 + lhi * 8]);
      acc = __builtin_amdgcn_mfma_f32_16x16x32_bf16(av, bv, acc, 0, 0, 0);
    }
    const int c = c0 + l15;
#pragma unroll
    for (int r = 0; r < 4; ++r) {
      int px = 16 * mt + lhi * 4 + r;
      SZ[px * 97 + c] = acc[r];
    }
  }
  __syncthreads();

  // --- 4. z = proj + x (x already in registers) ---
#pragma unroll
  for (int it = 0; it < 12; ++it) {
    int f = tid + it * 256;
    int c = f >> 5, pp = f & 31;
    SZ[pp * 97 + c] += xr[it];
  }
  __syncthreads();

  // --- 5. LN(96) on z -> SM (bf16) ---
  {
    const int pp = tid >> 3, t8 = tid & 7;
    float s = 0.f;
    for (int c = t8 * 12; c < t8 * 12 + 12; ++c) s += SZ[pp * 97 + c];
    s += __shfl_xor(s, 1, 8); s += __shfl_xor(s, 2, 8); s += __shfl_xor(s, 4, 8);
    float m = s * (1.f / 96.f);
    float v = 0.f;
    for (int c = t8 * 12; c < t8 * 12 + 12; ++c) {
      float t = SZ[pp * 97 + c] - m; v += t * t;
    }
    v += __shfl_xor(v, 1, 8); v += __shfl_xor(v, 2, 8); v += __shfl_xor(v, 4, 8);
    float rs = rsqrtf(v * (1.f / 96.f) + 1e-5f);
    for (int c = t8 * 12; c < t8 * 12 + 12; ++c)
      SM[pp * 104 + c] = f2bf((SZ[pp * 97 + c] - m) * rs * g2[c] + b2[c]);
  }
  __syncthreads();

  // --- 6/7. fc1+gelu / fc2 over two 192-halves; fc2 acc in registers ---
  f32x4 acc2[3];
#pragma unroll
  for (int q = 0; q < 3; ++q) acc2[q] = (f32x4){0.f, 0.f, 0.f, 0.f};

  for (int hlf = 0; hlf < 2; ++hlf) {
    {
      const int mt = wv & 1;
      const int ngrp = (wv >> 1) * 6;
      for (int t = 0; t < 6; ++t) {
        const int n0 = (ngrp + t) * 16;
        f32x4 acc = {0.f, 0.f, 0.f, 0.f};
#pragma unroll
        for (int kk = 0; kk < 3; ++kk) {
          short8 av = *reinterpret_cast<const short8*>(
              &SM[(16 * mt + l15) * 104 + kk * 32 + lhi * 8]);
          short8 bv = *reinterpret_cast<const short8*>(
              &w1b[(size_t)(hlf * 192 + n0 + l15) * 96 + kk * 32 + lhi * 8]);
          acc = __builtin_amdgcn_mfma_f32_16x16x32_bf16(av, bv, acc, 0, 0, 0);
        }
        const int jl = n0 + l15;
        const float bj = b1f[hlf * 192 + jl];
#pragma unroll
        for (int r = 0; r < 4; ++r) {
          int px = 16 * mt + lhi * 4 + r;
          SH[px * 200 + jl] = f2bf(geluf_(acc[r] + bj));
        }
      }
    }
    __syncthreads();
    for (int q = 0; q < 3; ++q) {
      const int tt = wv + q * 4;
      const int mt = tt & 1, c0 = (tt >> 1) * 16;
#pragma unroll
      for (int kk = 0; kk < 6; ++kk) {
        short8 av = *reinterpret_cast<const short8*>(
            &SH[(16 * mt + l15) * 200 + kk * 32 + lhi * 8]);
        short8 bv = *reinterpret_cast<const short8*>(
            &w2b[(size_t)(c0 + l15) * 384 + hlf * 192 + kk * 32 + lhi * 8]);
        acc2[q] = __builtin_amdgcn_mfma_f32_16x16x32_bf16(av, bv, acc2[q], 0, 0, 0);
      }
    }
    __syncthreads();
  }

  for (int q = 0; q < 3; ++q) {
    const int tt = wv + q * 4;
    const int mt = tt & 1, c0 = (tt >> 1) * 16;
    const int c = c0 + l15;
    const float bc = b2f[c];
#pragma unroll
    for (int r = 0; r < 4; ++r) {
      int px = 16 * mt + lhi * 4 + r;
      SMLP[px * 97 + c] = acc2[q][r] + bc;
    }
  }
  __syncthreads();

#pragma unroll
  for (int it = 0; it < 12; ++it) {
    int f = tid + it * 256;
    int c = f >> 5, pp = f & 31;
    out[((size_t)b * Cn + c) * Ln + pl0 + pp] =
        xr[it] + SZ[pp * 97 + c] + SMLP[pp * 97 + c];
  }
}

}  // namespace

extern "C" void kernel_launch(void* const* d_in, const int* in_sizes, int n_in,
                              void* d_out, int out_size, void* d_ws,
                              size_t ws_size, hipStream_t stream) {
  const float* x        = (const float*)d_in[0];
  const float* norm1_g  = (const float*)d_in[1];
  const float* norm1_b  = (const float*)d_in[2];
  const float* in_proj  = (const float*)d_in[3];
  const float* conv_w   = (const float*)d_in[4];
  const float* x_proj   = (const float*)d_in[5];
  const float* dt_w     = (const float*)d_in[6];
  const float* dt_b     = (const float*)d_in[7];
  const float* A_logs   = (const float*)d_in[8];
  const float* Ds       = (const float*)d_in[9];
  const float* onorm_g  = (const float*)d_in[10];
  const float* onorm_b  = (const float*)d_in[11];
  const float* out_proj = (const float*)d_in[12];
  const float* norm2_g  = (const float*)d_in[13];
  const float* norm2_b  = (const float*)d_in[14];
  const float* fc1_w    = (const float*)d_in[15];
  const float* fc1_b    = (const float*)d_in[16];
  const float* fc2_w    = (const float*)d_in[17];
  const float* fc2_b    = (const float*)d_in[18];
  float* out = (float*)d_out;

  float* ws = (float*)d_ws;
  size_t o = 0;
  float* apb  = ws + o; o += (size_t)Bn * Kn * NCH * Din;
  float* heb  = ws + o; o += (size_t)Bn * Kn * NCH * Din;
  float* cin  = ws + o; o += (size_t)Bn * Kn * NCH * Din;
  unsigned short* ucpb = (unsigned short*)(ws + o); o += (size_t)Bn * Din * Ln / 2;
  unsigned short* utb  = (unsigned short*)(ws + o); o += (size_t)Bn * Ln * Din / 2;
  unsigned short* yd   = (unsigned short*)(ws + o); o += (size_t)Bn * Kn * Ln * Din / 2;
  unsigned short* pcg  = (unsigned short*)(ws + o); o += (size_t)Bn * Kn * Ln * Din / 2;
  unsigned short* w1b = (unsigned short*)(ws + o); o += 36864 / 2;
  unsigned short* w2b = (unsigned short*)(ws + o); o += 36864 / 2;
  unsigned short* woutb = (unsigned short*)(ws + o); o += 18432 / 2;
  unsigned short* wxpb = (unsigned short*)(ws + o); o += 6144 / 2;

  k1_ln_inproj<<<536, 256, 0, stream>>>(x, norm1_g, norm1_b, in_proj, x_proj,
                                        ucpb, wxpb);
  k2a_conv<<<Bn * Hn * 2, 512, 0, stream>>>(ucpb, conv_w, utb);
  k4_scanY<<<Bn * Kn * NCH, 192, 0, stream>>>(utb, wxpb, dt_w, dt_b, A_logs,
                                              Ds, apb, heb, yd, pcg);
  k5_carry<<<372, 256, 0, stream>>>(apb, heb, cin, fc1_w, fc2_w, out_proj,
                                    w1b, w2b, woutb);
  k78_tail<<<512, 256, 0, stream>>>(yd, pcg, cin, onorm_g, onorm_b, woutb,
                                    norm2_g, norm2_b, w1b, fc1_b, w2b, fc2_b,
                                    x, out);
}

// Round 21
// 89.563 us; speedup vs baseline: 1.0232x; 1.0232x over previous
//
#include <hip/hip_runtime.h>
#include <math.h>

namespace {

constexpr int Bn = 4, Cn = 96, Hn = 64, Wn = 64, Ln = 4096, Din = 192;
constexpr int Kn = 4, Rn = 6, Dmlp = 384;
constexpr int NCH = 128, CLEN = 32;   // 128 chunks * 32 = L

typedef short short8 __attribute__((ext_vector_type(8)));
typedef float f32x4 __attribute__((ext_vector_type(4)));

__device__ __forceinline__ float siluf_(float x) {
  return x / (1.f + __expf(-x));
}
__device__ __forceinline__ float geluf_(float x) {
  return 0.5f * x * (1.f + erff(x * 0.7071067811865476f));
}
__device__ __forceinline__ unsigned short f2bf(float f) {
  unsigned u = __float_as_uint(f);
  unsigned r = 0x7fffu + ((u >> 16) & 1u);
  return (unsigned short)((u + r) >> 16);
}
__device__ __forceinline__ float bf2f(unsigned short v) {
  return __uint_as_float(((unsigned)v) << 16);
}

// ---------------------------------------------------------------------------
// K1: blocks 0..511: LayerNorm(96) + in_proj MFMA; outputs staged in LDS and
// written with coalesced short8 stores. Blocks 512..535: convert x_proj.
// LDS union: sx f32[32*97] (12416B) -> sout bf16[192][40] (15360B).
// ---------------------------------------------------------------------------
__global__ __launch_bounds__(256) void k1_ln_inproj(
    const float* __restrict__ x, const float* __restrict__ gam,
    const float* __restrict__ bet, const float* __restrict__ win,
    const float* __restrict__ wxp, unsigned short* __restrict__ ucpb,
    unsigned short* __restrict__ wxpb) {
  const int tid = threadIdx.x;
  if (blockIdx.x >= 512) {
    int t = (blockIdx.x - 512) * 256 + tid;   // [0, 6144)
    wxpb[t] = f2bf(wxp[t]);
    return;
  }

  __shared__ __align__(16) char su_mem[15360];
  float* sx = (float*)su_mem;                      // [32][97]
  unsigned short* sout = (unsigned short*)su_mem;  // [192][40]
  __shared__ __align__(16) unsigned short smb[32 * 104];
  __shared__ __align__(16) unsigned short swin[192 * 96];
  const int p0 = blockIdx.x * 32;
  const int b = p0 >> 12, pl0 = p0 & (Ln - 1);

  for (int e = tid; e < 4608; e += 256) {
    float4 w4 = reinterpret_cast<const float4*>(win)[e];
    uint2 pk;
    pk.x = (unsigned)f2bf(w4.x) | ((unsigned)f2bf(w4.y) << 16);
    pk.y = (unsigned)f2bf(w4.z) | ((unsigned)f2bf(w4.w) << 16);
    *reinterpret_cast<uint2*>(&swin[e * 4]) = pk;
  }

  for (int f = tid; f < 32 * 96; f += 256) {
    int c = f >> 5, pp = f & 31;
    sx[pp * 97 + c] = x[((size_t)b * Cn + c) * Ln + pl0 + pp];
  }
  __syncthreads();
  {
    const int pp = tid >> 3, t8 = tid & 7;
    float s = 0.f;
    for (int c = t8 * 12; c < t8 * 12 + 12; ++c) s += sx[pp * 97 + c];
    s += __shfl_xor(s, 1, 8); s += __shfl_xor(s, 2, 8); s += __shfl_xor(s, 4, 8);
    float m = s * (1.f / 96.f);
    float v = 0.f;
    for (int c = t8 * 12; c < t8 * 12 + 12; ++c) {
      float t = sx[pp * 97 + c] - m; v += t * t;
    }
    v += __shfl_xor(v, 1, 8); v += __shfl_xor(v, 2, 8); v += __shfl_xor(v, 4, 8);
    float rs = rsqrtf(v * (1.f / 96.f) + 1e-5f);
    for (int c = t8 * 12; c < t8 * 12 + 12; ++c)
      sx[pp * 97 + c] = (sx[pp * 97 + c] - m) * rs * gam[c] + bet[c];
  }
  __syncthreads();
  for (int f = tid; f < 32 * 96; f += 256) {
    int pp = f / 96, c = f % 96;
    smb[pp * 104 + c] = f2bf(sx[pp * 97 + c]);
  }
  __syncthreads();   // sx dead from here; sout may overwrite its region

  const int wv = tid >> 6, lane = tid & 63;
  const int l15 = lane & 15, lhi = lane >> 4;
  const int mt = wv & 1, nbase = (wv >> 1) * 6;
  for (int t = 0; t < 6; ++t) {
    const int n0 = (nbase + t) * 16;
    f32x4 acc = {0.f, 0.f, 0.f, 0.f};
#pragma unroll
    for (int kk = 0; kk < 3; ++kk) {
      short8 av = *reinterpret_cast<const short8*>(
          &smb[(16 * mt + l15) * 104 + kk * 32 + lhi * 8]);
      short8 bv = *reinterpret_cast<const short8*>(
          &swin[(n0 + l15) * 96 + kk * 32 + lhi * 8]);
      acc = __builtin_amdgcn_mfma_f32_16x16x32_bf16(av, bv, acc, 0, 0, 0);
    }
    const int j = n0 + l15;
#pragma unroll
    for (int r = 0; r < 4; ++r)
      sout[j * 40 + 16 * mt + lhi * 4 + r] = f2bf(acc[r]);
  }
  __syncthreads();

  // cooperative coalesced store: 4 lanes cover one channel's 64B row
  for (int f = tid; f < 768; f += 256) {
    int c = f >> 2, seg = (f & 3) * 8;
    short8 v = *reinterpret_cast<const short8*>(&sout[c * 40 + seg]);
    *reinterpret_cast<short8*>(
        &ucpb[((size_t)b * Din + c) * Ln + pl0 + seg]) = v;
  }
}

// ---------------------------------------------------------------------------
// K2a: depthwise 3x3 conv + SiLU -> utb (pixel-major bf16). Channel-split.
// ---------------------------------------------------------------------------
__global__ __launch_bounds__(512) void k2a_conv(
    const unsigned short* __restrict__ ucpb, const float* __restrict__ cw,
    unsigned short* __restrict__ utb) {
  __shared__ float su[64 * 97];
  const int tid = threadIdx.x;
  const int bid = blockIdx.x;
  const int half = bid & 1, bh = bid >> 1;
  const int b = bh >> 6, h = bh & 63;
  const int w = tid & 63, wg = tid >> 6;
  const int d0 = half * 96;

  for (int dd = 0; dd < 12; ++dd) {
    int dl = wg * 12 + dd;
    int d = d0 + dl;
    const unsigned short* base = &ucpb[((size_t)b * Din + d) * Ln];
    float r0 = (h > 0) ? bf2f(base[(h - 1) * 64 + w]) : 0.f;
    float r1 = bf2f(base[h * 64 + w]);
    float r2 = (h < 63) ? bf2f(base[(h + 1) * 64 + w]) : 0.f;
    const float* wt = &cw[d * 9];
    float rl, rr, acc;
    rl = __shfl(r0, (w + 63) & 63); if (w == 0) rl = 0.f;
    rr = __shfl(r0, (w + 1) & 63);  if (w == 63) rr = 0.f;
    acc = rl * wt[0] + r0 * wt[1] + rr * wt[2];
    rl = __shfl(r1, (w + 63) & 63); if (w == 0) rl = 0.f;
    rr = __shfl(r1, (w + 1) & 63);  if (w == 63) rr = 0.f;
    acc += rl * wt[3] + r1 * wt[4] + rr * wt[5];
    rl = __shfl(r2, (w + 63) & 63); if (w == 0) rl = 0.f;
    rr = __shfl(r2, (w + 1) & 63);  if (w == 63) rr = 0.f;
    acc += rl * wt[6] + r2 * wt[7] + rr * wt[8];
    su[w * 97 + dl] = siluf_(acc);
  }
  __syncthreads();

  for (int f = tid; f < 768; f += 512) {
    int pp = f / 12, c8 = (f % 12) * 8;
    short8 v;
#pragma unroll
    for (int j = 0; j < 8; ++j) v[j] = (short)f2bf(su[pp * 97 + c8 + j]);
    *reinterpret_cast<short8*>(
        &utb[((size_t)b * Ln + h * 64 + pp) * Din + d0 + c8]) = v;
  }
}

__device__ __forceinline__ int scan_pixel(int k, int l) {
  if (k == 0) return l;
  if (k == 1) return ((l & 63) << 6) | (l >> 6);
  if (k == 2) return Ln - 1 - l;
  int m2 = Ln - 1 - l;
  return ((m2 & 63) << 6) | (m2 >> 6);
}

// ---------------------------------------------------------------------------
// Shared scan-block prologue: stage chunk's u rows (scan order) into LDS,
// compute own-direction x_proj via MFMA into sdb[32][8].
// ---------------------------------------------------------------------------
__device__ __forceinline__ void scan_stage(
    const unsigned short* __restrict__ ub,
    const unsigned short* __restrict__ wxpb, int k, int l0, int d,
    unsigned short* su, float* sdb) {
  for (int e = d; e < 768; e += 192) {
    int i = e / 24, c8 = (e % 24) * 8;
    int p = scan_pixel(k, l0 + i);
    *reinterpret_cast<short8*>(&su[i * 200 + c8]) =
        *reinterpret_cast<const short8*>(&ub[(size_t)p * 192 + c8]);
  }
  __syncthreads();
  const int wv3 = d >> 6, lane = d & 63;
  const int l15 = lane & 15, lhi = lane >> 4;
  if (wv3 < 2) {
    const int mt = wv3;
    const int n0 = (k >> 1) * 16;
    f32x4 acc = {0.f, 0.f, 0.f, 0.f};
#pragma unroll
    for (int kk = 0; kk < 6; ++kk) {
      short8 av = *reinterpret_cast<const short8*>(
          &su[(16 * mt + l15) * 200 + kk * 32 + lhi * 8]);
      short8 bv = *reinterpret_cast<const short8*>(
          &wxpb[(size_t)(n0 + l15) * 192 + kk * 32 + lhi * 8]);
      acc = __builtin_amdgcn_mfma_f32_16x16x32_bf16(av, bv, acc, 0, 0, 0);
    }
    if ((l15 >> 3) == (k & 1)) {
      const int c8 = l15 & 7;
#pragma unroll
      for (int r = 0; r < 4; ++r)
        sdb[(16 * mt + lhi * 4 + r) * 8 + c8] = acc[r];
    }
  }
  __syncthreads();
}

// ---------------------------------------------------------------------------
// K4: single heavy scan pass — fused x_proj + local carry-free scan.
// Av == -1 exact fast path: a = 1/(1+e^x) via v_rcp (one exp saved/elem).
// ys LDS-staged writeout (vectorized short8 stores).
// ---------------------------------------------------------------------------
__global__ __launch_bounds__(192) void k4_scanY(
    const unsigned short* __restrict__ utb,
    const unsigned short* __restrict__ wxpb, const float* __restrict__ wdtg,
    const float* __restrict__ bdtg, const float* __restrict__ alog,
    const float* __restrict__ dsg, float* __restrict__ apb,
    float* __restrict__ heb, unsigned short* __restrict__ yd,
    unsigned short* __restrict__ pcg) {
  __shared__ __align__(16) unsigned short su[32 * 200];
  __shared__ __align__(16) float sdb[CLEN * 8];
  __shared__ __align__(16) unsigned short ys[CLEN * 192];
  const int bid = blockIdx.x;
  const int ch = bid & (NCH - 1);
  const int bk = bid / NCH;
  const int b = bk >> 2, k = bk & 3;
  const int d = threadIdx.x;
  const int l0 = ch * CLEN;

  float wdt[6];
#pragma unroll
  for (int r = 0; r < 6; ++r) wdt[r] = wdtg[(k * Din + d) * 6 + r];
  const float bdt = bdtg[k * Din + d];
  const float Av = -__expf(alog[k * Din + d]);
  const bool fast = (Av == -1.0f);
  const float Dv = dsg[k * Din + d];
  unsigned short* yk = &yd[(size_t)bk * Ln * Din];
  unsigned short* pk = &pcg[(size_t)bk * Ln * Din];

  scan_stage(&utb[(size_t)b * Ln * Din], wxpb, k, l0, d, su, sdb);

  float h = 0.f, P = 1.f;
  for (int i0 = 0; i0 < CLEN; i0 += 8) {
    float U[8];
#pragma unroll
    for (int j = 0; j < 8; ++j) U[j] = bf2f(su[(i0 + j) * 200 + d]);
#pragma unroll
    for (int j = 0; j < 8; ++j) {
      float4 qa = *reinterpret_cast<const float4*>(&sdb[(i0 + j) * 8]);
      float4 qb = *reinterpret_cast<const float4*>(&sdb[(i0 + j) * 8 + 4]);
      float xdt = bdt;
      xdt = fmaf(qa.x, wdt[0], xdt); xdt = fmaf(qa.y, wdt[1], xdt);
      xdt = fmaf(qa.z, wdt[2], xdt); xdt = fmaf(qa.w, wdt[3], xdt);
      xdt = fmaf(qb.x, wdt[4], xdt); xdt = fmaf(qb.y, wdt[5], xdt);
      float ex = __expf(-fabsf(xdt));
      float dt = fmaxf(xdt, 0.f) + __logf(1.f + ex);
      float a;
      if (fast) {
        float num = (xdt > 0.f) ? ex : 1.f;
        a = num * __builtin_amdgcn_rcpf(1.f + ex);
      } else {
        a = __expf(dt * Av);
      }
      float bbv = dt * qb.z * U[j];
      h = fmaf(a, h, bbv);
      P *= a;
      ys[(i0 + j) * 192 + d] = f2bf(h * qb.w + Dv * U[j]);
      pk[(size_t)(l0 + i0 + j) * 192 + d] = f2bf(P * qb.w);
    }
  }
  size_t o = ((size_t)bk * NCH + ch) * Din + d;
  apb[o] = P;
  heb[o] = h;
  __syncthreads();
  for (int e = d; e < CLEN * 24; e += 192) {
    *reinterpret_cast<short8*>(&yk[(size_t)l0 * 192 + e * 8]) =
        *reinterpret_cast<const short8*>(&ys[e * 8]);
  }
}

// ---------------------------------------------------------------------------
// K5: blocks 0..11: chunk carries with batch-8 prefetch (breaks the
// load-latency-serial chain). Blocks 12..371: convert w1/w2/wout to bf16.
// ---------------------------------------------------------------------------
__global__ __launch_bounds__(256) void k5_carry(
    const float* __restrict__ apb, const float* __restrict__ heb,
    float* __restrict__ cin, const float* __restrict__ w1,
    const float* __restrict__ w2, const float* __restrict__ wout,
    unsigned short* __restrict__ w1b, unsigned short* __restrict__ w2b,
    unsigned short* __restrict__ woutb) {
  if (blockIdx.x >= 12) {
    int t = (blockIdx.x - 12) * 256 + threadIdx.x;   // [0, 92160)
    if (t < 36864) w1b[t] = f2bf(w1[t]);
    else if (t < 73728) w2b[t - 36864] = f2bf(w2[t - 36864]);
    else woutb[t - 73728] = f2bf(wout[t - 73728]);
    return;
  }
  int t = blockIdx.x * 256 + threadIdx.x;
  if (t >= Bn * Kn * Din) return;
  int bk = t / Din, d = t % Din;
  const float* ap_ = &apb[(size_t)bk * NCH * Din + d];
  const float* hp_ = &heb[(size_t)bk * NCH * Din + d];
  float* cp_ = &cin[(size_t)bk * NCH * Din + d];
  float c = 0.f;
  for (int ch = 0; ch < NCH; ch += 8) {
    float A[8], H[8];
#pragma unroll
    for (int j = 0; j < 8; ++j) {
      A[j] = ap_[(size_t)(ch + j) * Din];
      H[j] = hp_[(size_t)(ch + j) * Din];
    }
#pragma unroll
    for (int j = 0; j < 8; ++j) {
      cp_[(size_t)(ch + j) * Din] = c;
      c = fmaf(A[j], c, H[j]);
    }
  }
}

// ---------------------------------------------------------------------------
// K78: fused tail (R16 f32-LDS form). Phase 1 merge applies carry correction.
// ---------------------------------------------------------------------------
__global__ __launch_bounds__(256) void k78_tail(
    const unsigned short* __restrict__ yd,
    const unsigned short* __restrict__ pcg, const float* __restrict__ cin,
    const float* __restrict__ gam, const float* __restrict__ bet,
    const unsigned short* __restrict__ woutb, const float* __restrict__ g2,
    const float* __restrict__ b2, const unsigned short* __restrict__ w1b,
    const float* __restrict__ b1f, const unsigned short* __restrict__ w2b,
    const float* __restrict__ b2f, const float* __restrict__ x,
    float* __restrict__ out) {
  __shared__ __align__(16) char smem[50304];
  float* SY = (float*)smem;
  unsigned short* SB7 = (unsigned short*)(smem + 24704);
  unsigned short* SH = (unsigned short*)(smem + 37504);
  float* SZ = (float*)smem;
  unsigned short* SM = (unsigned short*)(smem + 12416);
  float* SMLP = (float*)(smem + 24704);

  const int tid = threadIdx.x;
  const int p0 = blockIdx.x * 32;
  const int b = p0 >> 12, pl0 = p0 & (Ln - 1);
  const int wv = tid >> 6, lane = tid & 63;
  const int l15 = lane & 15, lhi = lane >> 4;

  // --- 1. merge 4 directions with carry correction -> SY ---
  for (int f = tid; f < 32 * 24; f += 256) {
    int pp = f / 24, c8 = (f % 24) * 8;
    int p = pl0 + pp;
    int l1 = ((p & 63) << 6) | (p >> 6);
    float s[8];
#pragma unroll
    for (int j = 0; j < 8; ++j) s[j] = 0.f;
#pragma unroll
    for (int k = 0; k < 4; ++k) {
      int l = (k == 0) ? p : (k == 1) ? l1 : (k == 2) ? (Ln - 1 - p)
                                                      : (Ln - 1 - l1);
      size_t base = ((size_t)(b * 4 + k) * Ln + l) * 192 + c8;
      short8 py = *reinterpret_cast<const short8*>(&yd[base]);
      short8 pc = *reinterpret_cast<const short8*>(&pcg[base]);
      const float* cp =
          &cin[((size_t)(b * 4 + k) * NCH + (l >> 5)) * 192 + c8];
      float4 ca = *reinterpret_cast<const float4*>(cp);
      float4 cb = *reinterpret_cast<const float4*>(cp + 4);
      float cv[8] = {ca.x, ca.y, ca.z, ca.w, cb.x, cb.y, cb.z, cb.w};
#pragma unroll
      for (int j = 0; j < 8; ++j)
        s[j] += bf2f((unsigned short)py[j]) +
                bf2f((unsigned short)pc[j]) * cv[j];
    }
#pragma unroll
    for (int j = 0; j < 8; ++j) SY[pp * 193 + c8 + j] = s[j];
  }
  __syncthreads();

  // --- 2. LN(192) -> SB7 (bf16) ---
  {
    const int pp = tid >> 3, t8 = tid & 7;
    float s = 0.f;
    for (int d2 = t8 * 24; d2 < t8 * 24 + 24; ++d2) s += SY[pp * 193 + d2];
    s += __shfl_xor(s, 1, 8); s += __shfl_xor(s, 2, 8); s += __shfl_xor(s, 4, 8);
    float m = s * (1.f / 192.f);
    float v = 0.f;
    for (int d2 = t8 * 24; d2 < t8 * 24 + 24; ++d2) {
      float t = SY[pp * 193 + d2] - m; v += t * t;
    }
    v += __shfl_xor(v, 1, 8); v += __shfl_xor(v, 2, 8); v += __shfl_xor(v, 4, 8);
    float rs = rsqrtf(v * (1.f / 192.f) + 1e-5f);
    for (int d2 = t8 * 24; d2 < t8 * 24 + 24; ++d2)
      SB7[pp * 200 + d2] = f2bf((SY[pp * 193 + d2] - m) * rs * gam[d2] + bet[d2]);
  }
  __syncthreads();

  // --- 3. out_proj MFMA (K=192) -> SZ ---
  for (int q = 0; q < 3; ++q) {
    const int tt = wv + q * 4;
    const int mt = tt & 1, c0 = (tt >> 1) * 16;
    f32x4 acc = {0.f, 0.f, 0.f, 0.f};
#pragma unroll
    for (int kk = 0; kk < 6; ++kk) {
      short8 av = *reinterpret_cast<const short8*>(
          &SB7[(16 * mt + l15) * 200 + kk * 32 + lhi * 8]);
      short8 bv = *reinterpret_cast<const short8*>(
          &woutb[(size_t)(c0 + l15) * 192 + kk * 32 + lhi * 8]);
      acc = __builtin_amdgcn_mfma_f32_16x16x32_bf16(av, bv, acc, 0, 0, 0);
    }
    const int c = c0 + l15;
#pragma unroll
    for (int r = 0; r < 4; ++r) {
      int px = 16 * mt + lhi * 4 + r;
      SZ[px * 97 + c] = acc[r];
    }
  }
  __syncthreads();

  // --- 4. z = proj + x ---
  float xr[12];
#pragma unroll
  for (int it = 0; it < 12; ++it) {
    int f = tid + it * 256;
    int c = f >> 5, pp = f & 31;
    xr[it] = x[((size_t)b * Cn + c) * Ln + pl0 + pp];
    SZ[pp * 97 + c] += xr[it];
  }
  __syncthreads();

  // --- 5. LN(96) on z -> SM (bf16) ---
  {
    const int pp = tid >> 3, t8 = tid & 7;
    float s = 0.f;
    for (int c = t8 * 12; c < t8 * 12 + 12; ++c) s += SZ[pp * 97 + c];
    s += __shfl_xor(s, 1, 8); s += __shfl_xor(s, 2, 8); s += __shfl_xor(s, 4, 8);
    float m = s * (1.f / 96.f);
    float v = 0.f;
    for (int c = t8 * 12; c < t8 * 12 + 12; ++c) {
      float t = SZ[pp * 97 + c] - m; v += t * t;
    }
    v += __shfl_xor(v, 1, 8); v += __shfl_xor(v, 2, 8); v += __shfl_xor(v, 4, 8);
    float rs = rsqrtf(v * (1.f / 96.f) + 1e-5f);
    for (int c = t8 * 12; c < t8 * 12 + 12; ++c)
      SM[pp * 104 + c] = f2bf((SZ[pp * 97 + c] - m) * rs * g2[c] + b2[c]);
  }
  __syncthreads();

  // --- 6/7. fc1+gelu / fc2 over two 192-halves; fc2 acc in registers ---
  f32x4 acc2[3];
#pragma unroll
  for (int q = 0; q < 3; ++q) acc2[q] = (f32x4){0.f, 0.f, 0.f, 0.f};

  for (int hlf = 0; hlf < 2; ++hlf) {
    {
      const int mt = wv & 1;
      const int ngrp = (wv >> 1) * 6;
      for (int t = 0; t < 6; ++t) {
        const int n0 = (ngrp + t) * 16;
        f32x4 acc = {0.f, 0.f, 0.f, 0.f};
#pragma unroll
        for (int kk = 0; kk < 3; ++kk) {
          short8 av = *reinterpret_cast<const short8*>(
              &SM[(16 * mt + l15) * 104 + kk * 32 + lhi * 8]);
          short8 bv = *reinterpret_cast<const short8*>(
              &w1b[(size_t)(hlf * 192 + n0 + l15) * 96 + kk * 32 + lhi * 8]);
          acc = __builtin_amdgcn_mfma_f32_16x16x32_bf16(av, bv, acc, 0, 0, 0);
        }
        const int jl = n0 + l15;
        const float bj = b1f[hlf * 192 + jl];
#pragma unroll
        for (int r = 0; r < 4; ++r) {
          int px = 16 * mt + lhi * 4 + r;
          SH[px * 200 + jl] = f2bf(geluf_(acc[r] + bj));
        }
      }
    }
    __syncthreads();
    for (int q = 0; q < 3; ++q) {
      const int tt = wv + q * 4;
      const int mt = tt & 1, c0 = (tt >> 1) * 16;
#pragma unroll
      for (int kk = 0; kk < 6; ++kk) {
        short8 av = *reinterpret_cast<const short8*>(
            &SH[(16 * mt + l15) * 200 + kk * 32 + lhi * 8]);
        short8 bv = *reinterpret_cast<const short8*>(
            &w2b[(size_t)(c0 + l15) * 384 + hlf * 192 + kk * 32 + lhi * 8]);
        acc2[q] = __builtin_amdgcn_mfma_f32_16x16x32_bf16(av, bv, acc2[q], 0, 0, 0);
      }
    }
    __syncthreads();
  }

  for (int q = 0; q < 3; ++q) {
    const int tt = wv + q * 4;
    const int mt = tt & 1, c0 = (tt >> 1) * 16;
    const int c = c0 + l15;
    const float bc = b2f[c];
#pragma unroll
    for (int r = 0; r < 4; ++r) {
      int px = 16 * mt + lhi * 4 + r;
      SMLP[px * 97 + c] = acc2[q][r] + bc;
    }
  }
  __syncthreads();

#pragma unroll
  for (int it = 0; it < 12; ++it) {
    int f = tid + it * 256;
    int c = f >> 5, pp = f & 31;
    out[((size_t)b * Cn + c) * Ln + pl0 + pp] =
        xr[it] + SZ[pp * 97 + c] + SMLP[pp * 97 + c];
  }
}

}  // namespace

extern "C" void kernel_launch(void* const* d_in, const int* in_sizes, int n_in,
                              void* d_out, int out_size, void* d_ws,
                              size_t ws_size, hipStream_t stream) {
  const float* x        = (const float*)d_in[0];
  const float* norm1_g  = (const float*)d_in[1];
  const float* norm1_b  = (const float*)d_in[2];
  const float* in_proj  = (const float*)d_in[3];
  const float* conv_w   = (const float*)d_in[4];
  const float* x_proj   = (const float*)d_in[5];
  const float* dt_w     = (const float*)d_in[6];
  const float* dt_b     = (const float*)d_in[7];
  const float* A_logs   = (const float*)d_in[8];
  const float* Ds       = (const float*)d_in[9];
  const float* onorm_g  = (const float*)d_in[10];
  const float* onorm_b  = (const float*)d_in[11];
  const float* out_proj = (const float*)d_in[12];
  const float* norm2_g  = (const float*)d_in[13];
  const float* norm2_b  = (const float*)d_in[14];
  const float* fc1_w    = (const float*)d_in[15];
  const float* fc1_b    = (const float*)d_in[16];
  const float* fc2_w    = (const float*)d_in[17];
  const float* fc2_b    = (const float*)d_in[18];
  float* out = (float*)d_out;

  float* ws = (float*)d_ws;
  size_t o = 0;
  float* apb  = ws + o; o += (size_t)Bn * Kn * NCH * Din;
  float* heb  = ws + o; o += (size_t)Bn * Kn * NCH * Din;
  float* cin  = ws + o; o += (size_t)Bn * Kn * NCH * Din;
  unsigned short* ucpb = (unsigned short*)(ws + o); o += (size_t)Bn * Din * Ln / 2;
  unsigned short* utb  = (unsigned short*)(ws + o); o += (size_t)Bn * Ln * Din / 2;
  unsigned short* yd   = (unsigned short*)(ws + o); o += (size_t)Bn * Kn * Ln * Din / 2;
  unsigned short* pcg  = (unsigned short*)(ws + o); o += (size_t)Bn * Kn * Ln * Din / 2;
  unsigned short* w1b = (unsigned short*)(ws + o); o += 36864 / 2;
  unsigned short* w2b = (unsigned short*)(ws + o); o += 36864 / 2;
  unsigned short* woutb = (unsigned short*)(ws + o); o += 18432 / 2;
  unsigned short* wxpb = (unsigned short*)(ws + o); o += 6144 / 2;

  k1_ln_inproj<<<536, 256, 0, stream>>>(x, norm1_g, norm1_b, in_proj, x_proj,
                                        ucpb, wxpb);
  k2a_conv<<<Bn * Hn * 2, 512, 0, stream>>>(ucpb, conv_w, utb);
  k4_scanY<<<Bn * Kn * NCH, 192, 0, stream>>>(utb, wxpb, dt_w, dt_b, A_logs,
                                              Ds, apb, heb, yd, pcg);
  k5_carry<<<372, 256, 0, stream>>>(apb, heb, cin, fc1_w, fc2_w, out_proj,
                                    w1b, w2b, woutb);
  k78_tail<<<512, 256, 0, stream>>>(yd, pcg, cin, onorm_g, onorm_b, woutb,
                                    norm2_g, norm2_b, w1b, fc1_b, w2b, fc2_b,
                                    x, out);
}